// Round 17
// baseline (797.860 us; speedup 1.0000x reference)
//
#include <hip/hip_runtime.h>
#include <math.h>

// ---------------- compile-time sizes ----------------
namespace {
constexpr int B_ = 8, T_ = 128, D_ = 512, C_ = 1000, L_ = 8, U_ = 16, E_ = 256, H_ = 4;
constexpr int VOC_ = 5000;
constexpr int DH_ = D_ / H_;      // 128
constexpr int E4_ = 4 * E_;       // 1024
constexpr int D4_ = 4 * D_;       // 2048
constexpr int TU_ = T_ * U_;      // 2048
constexpr int HC_ = H_ * C_;      // 4000
constexpr float SCALE_ = 0.088388347648318447f; // 1/sqrt(128)

// XZ swizzle geometry
constexpr int XZ_NB  = E4_ / 64;            // 16 n-tiles (fastest)
constexpr int XZ_MB  = (VOC_ + 63) / 64;    // 79 m-tiles
constexpr int XZ_NWG = XZ_NB * XZ_MB;       // 1264
constexpr int XZ_CPX = XZ_NWG / 8;          // 158 per XCD

// ---------------- ws layout (float offsets) ----------------
constexpr size_t XZ_    = 0;
constexpr size_t SM_    = 0;                                   // B*T*H*C
constexpr size_t SH_    = SM_ + (size_t)B_ * T_ * HC_;         // B*U*H*C
constexpr size_t AOUT_  = SH_ + (size_t)B_ * U_ * HC_;         // B*T*D (unused now)
constexpr size_t PVP_   = AOUT_ + (size_t)B_ * T_ * D_;        // 8*1024*512 partials
constexpr size_t REG_A  = 2ul * VOC_ * E4_;
constexpr size_t HPING  = REG_A;                               // 2*C*E
constexpr size_t CST    = HPING + 2ul * C_ * E_;               // 2*C*E
constexpr size_t HPONG  = CST + 2ul * C_ * E_;
constexpr size_t HFALL  = HPONG + 2ul * C_ * E_;               // C*L*E
constexpr size_t HBALL  = HFALL + (size_t)C_ * L_ * E_;
constexpr size_t CATM   = HBALL + (size_t)C_ * L_ * E_;        // C*2E
constexpr size_t CTXM   = CATM + (size_t)C_ * 2 * E_;          // C*D
constexpr size_t KWS    = CTXM + (size_t)C_ * D_;
constexpr size_t VWS    = KWS + (size_t)C_ * D_;
constexpr size_t WQA    = VWS + (size_t)C_ * D_;               // D*D
constexpr size_t WQH    = WQA + (size_t)D_ * D_;               // D*D
constexpr size_t HXP    = WQH + (size_t)D_ * D_;               // B*U*4D
constexpr size_t HALL   = HXP + (size_t)B_ * U_ * D4_;         // B*U*D
constexpr size_t HGLOB  = HALL + (size_t)B_ * U_ * D_;         // B*D (h ping)
constexpr size_t HG2    = HGLOB + (size_t)B_ * D_;             // B*D (h pong)
constexpr size_t HISTC  = HG2 + (size_t)B_ * D_;               // B*D (c state)
constexpr size_t QM_    = HISTC + (size_t)B_ * D_;             // B*T*D
constexpr size_t QH_    = QM_ + (size_t)B_ * T_ * D_;          // B*U*D
constexpr size_t SMSUM  = QH_ + (size_t)B_ * U_ * D_;          // B*T*C
constexpr size_t SHSUM  = SMSUM + (size_t)B_ * T_ * C_;        // B*U*C
constexpr size_t DEN_   = SHSUM + (size_t)B_ * U_ * C_;        // B*T*U*H
constexpr size_t BITS_  = DEN_ + (size_t)B_ * T_ * U_ * H_;    // 16384 B
constexpr size_t USEL_  = BITS_ + 4096;
constexpr size_t PERM_  = USEL_ + (size_t)B_ * T_;             // C ints
constexpr size_t NACT_  = PERM_ + C_;                          // 8 ints
constexpr size_t WS_NEED = NACT_ + 8;
constexpr size_t PVSLAB = (size_t)B_ * T_ * D_;                // 524288
} // namespace

__device__ __forceinline__ float fsig(float x)  { return 1.f / (1.f + __expf(-x)); }
__device__ __forceinline__ float ftanh(float x) { return 1.f - 2.f / (__expf(2.f * x) + 1.f); }
__device__ __forceinline__ void fma4(float4& a, float w, const float4& v) {
  a.x += w * v.x; a.y += w * v.y; a.z += w * v.z; a.w += w * v.w;
}

// ---------------- generic NT GEMM (X @ W^T), 64 x TN tile, reg-prefetch pipeline ----------------
struct GemmP {
  const float* A1; int lda1;
  const int* ridx; int ridx_stride; int ridx_off;
  const float* W1; int ldw1;
  const float* bias;
  float* out; int ldc;
  int M, N, K;
  float scale;
  int a_zoff, w_zoff, c_zoff;
};

template <int TN>
__device__ __forceinline__ void gemm_core(const GemmP& g, int z, int by, int bx) {
  constexpr int UN = TN / 16;
  constexpr int WP = TN / 64;
  __shared__ float As[16][68];
  __shared__ float Ws[16][TN + 4];
  const int m0 = by * 64;
  const int n0 = bx * TN;
  if (m0 >= g.M || n0 >= g.N) return;
  const float* A1 = g.A1 + (long)z * g.a_zoff;
  const float* W1 = g.W1 + (long)z * g.w_zoff;
  float* out = g.out + (long)z * g.c_zoff;
  const int tid = threadIdx.x;
  const int tx = tid & 15, ty = tid >> 4;
  const int sr = tid >> 2, skq = (tid & 3) * 4;
  float acc[4][UN] = {};
  int sarow = -1;
  {
    const int gm = m0 + sr;
    if (gm < g.M) sarow = g.ridx ? g.ridx[gm * g.ridx_stride + g.ridx_off] : gm;
  }
  float4 pa, pw[WP];
  {
    pa = make_float4(0.f, 0.f, 0.f, 0.f);
    if (sarow >= 0) pa = *(const float4*)&A1[(long)sarow * g.lda1 + skq];
#pragma unroll
    for (int p = 0; p < WP; ++p) {
      const int gn = n0 + sr + p * 64;
      pw[p] = make_float4(0.f, 0.f, 0.f, 0.f);
      if (gn < g.N) pw[p] = *(const float4*)&W1[(long)gn * g.ldw1 + skq];
    }
  }
  for (int k0 = 0; k0 < g.K; k0 += 16) {
    As[skq][sr] = pa.x; As[skq + 1][sr] = pa.y; As[skq + 2][sr] = pa.z; As[skq + 3][sr] = pa.w;
#pragma unroll
    for (int p = 0; p < WP; ++p) {
      const int r = sr + p * 64;
      Ws[skq][r] = pw[p].x; Ws[skq + 1][r] = pw[p].y; Ws[skq + 2][r] = pw[p].z; Ws[skq + 3][r] = pw[p].w;
    }
    __syncthreads();
    const int kn = k0 + 16;
    if (kn < g.K) {
      pa = make_float4(0.f, 0.f, 0.f, 0.f);
      if (sarow >= 0) pa = *(const float4*)&A1[(long)sarow * g.lda1 + kn + skq];
#pragma unroll
      for (int p = 0; p < WP; ++p) {
        const int gn = n0 + sr + p * 64;
        pw[p] = make_float4(0.f, 0.f, 0.f, 0.f);
        if (gn < g.N) pw[p] = *(const float4*)&W1[(long)gn * g.ldw1 + kn + skq];
      }
    }
#pragma unroll
    for (int k = 0; k < 16; ++k) {
      const float4 a = *(const float4*)&As[k][ty * 4];
#pragma unroll
      for (int q = 0; q < UN / 4; ++q) {
        const float4 w = *(const float4*)&Ws[k][q * 64 + tx * 4];
        acc[0][q*4+0] += a.x * w.x; acc[0][q*4+1] += a.x * w.y; acc[0][q*4+2] += a.x * w.z; acc[0][q*4+3] += a.x * w.w;
        acc[1][q*4+0] += a.y * w.x; acc[1][q*4+1] += a.y * w.y; acc[1][q*4+2] += a.y * w.z; acc[1][q*4+3] += a.y * w.w;
        acc[2][q*4+0] += a.z * w.x; acc[2][q*4+1] += a.z * w.y; acc[2][q*4+2] += a.z * w.z; acc[2][q*4+3] += a.z * w.w;
        acc[3][q*4+0] += a.w * w.x; acc[3][q*4+1] += a.w * w.y; acc[3][q*4+2] += a.w * w.z; acc[3][q*4+3] += a.w * w.w;
      }
    }
    __syncthreads();
  }
#pragma unroll
  for (int i = 0; i < 4; ++i) {
    const int gm = m0 + ty * 4 + i;
    if (gm >= g.M) continue;
#pragma unroll
    for (int q = 0; q < UN / 4; ++q) {
#pragma unroll
      for (int j = 0; j < 4; ++j) {
        const int gn = n0 + q * 64 + tx * 4 + j;
        if (gn >= g.N) continue;
        float v2 = acc[i][q*4+j];
        if (g.bias) v2 += g.bias[gn];
        out[(long)gm * g.ldc + gn] = v2 * g.scale;
      }
    }
  }
}

__global__ __launch_bounds__(256) void k_gemm64(GemmP p)  { gemm_core<64>(p, blockIdx.z, blockIdx.y, blockIdx.x); }
__global__ __launch_bounds__(256) void k_gemm64x4(GemmP p0, GemmP p1, GemmP p2, GemmP p3) {
  int z = blockIdx.z;
  if (z == 0) gemm_core<64>(p0, 0, blockIdx.y, blockIdx.x);
  else if (z == 1) gemm_core<64>(p1, 0, blockIdx.y, blockIdx.x);
  else if (z == 2) gemm_core<64>(p2, 0, blockIdx.y, blockIdx.x);
  else gemm_core<64>(p3, 0, blockIdx.y, blockIdx.x);
}
__global__ __launch_bounds__(256) void k_gemm128x2(GemmP p0, GemmP p1, int zs) {
  int z = blockIdx.z;
  if (z < zs) gemm_core<128>(p0, z, blockIdx.y, blockIdx.x);
  else gemm_core<128>(p1, z - zs, blockIdx.y, blockIdx.x);
}
__global__ __launch_bounds__(256) void k_gemm64xcd(GemmP p0, GemmP p1) {
  const int bid = blockIdx.x;
  const int logical = (bid & 7) * XZ_CPX + (bid >> 3);
  const int bx = logical % XZ_NB;
  const int by = logical / XZ_NB;
  if (blockIdx.z == 0) gemm_core<64>(p0, 0, by, bx);
  else gemm_core<64>(p1, 0, by, bx);
}

// ---------------- Wo GEMM with fused 8-slab A reduction -> o ----------------
__global__ __launch_bounds__(256) void k_wo_red8(
    const float* __restrict__ pvp, const float* __restrict__ W,
    float* __restrict__ out) {
  __shared__ float As[16][68];
  __shared__ float Ws[16][68];
  const int m0 = blockIdx.y * 64, n0 = blockIdx.x * 64;
  const int tid = threadIdx.x;
  const int tx = tid & 15, ty = tid >> 4;
  const int sr = tid >> 2, skq = (tid & 3) * 4;
  float acc[4][4] = {};
  const float* arow = pvp + (long)(m0 + sr) * D_;
  const float* wrow = W + (long)(n0 + sr) * D_;
  for (int k0 = 0; k0 < D_; k0 += 16) {
    {
      float4 s = *(const float4*)&arow[k0 + skq];
#pragma unroll
      for (int k = 1; k < 8; ++k) {
        const float4 v = *(const float4*)&arow[(size_t)k * PVSLAB + k0 + skq];
        s.x += v.x; s.y += v.y; s.z += v.z; s.w += v.w;
      }
      As[skq][sr] = s.x; As[skq + 1][sr] = s.y; As[skq + 2][sr] = s.z; As[skq + 3][sr] = s.w;
    }
    {
      float4 w = *(const float4*)&wrow[k0 + skq];
      Ws[skq][sr] = w.x; Ws[skq + 1][sr] = w.y; Ws[skq + 2][sr] = w.z; Ws[skq + 3][sr] = w.w;
    }
    __syncthreads();
#pragma unroll
    for (int k = 0; k < 16; ++k) {
      const float4 a = *(const float4*)&As[k][ty * 4];
      const float4 w = *(const float4*)&Ws[k][tx * 4];
      acc[0][0] += a.x * w.x; acc[0][1] += a.x * w.y; acc[0][2] += a.x * w.z; acc[0][3] += a.x * w.w;
      acc[1][0] += a.y * w.x; acc[1][1] += a.y * w.y; acc[1][2] += a.y * w.z; acc[1][3] += a.y * w.w;
      acc[2][0] += a.z * w.x; acc[2][1] += a.z * w.y; acc[2][2] += a.z * w.z; acc[2][3] += a.z * w.w;
      acc[3][0] += a.w * w.x; acc[3][1] += a.w * w.y; acc[3][2] += a.w * w.z; acc[3][3] += a.w * w.w;
    }
    __syncthreads();
  }
#pragma unroll
  for (int i = 0; i < 4; ++i)
#pragma unroll
    for (int j = 0; j < 4; ++j)
      out[(long)(m0 + ty * 4 + i) * D_ + n0 + tx * 4 + j] = acc[i][j];
}

// ---------------- NN GEMM: O = A @ B, 512x512x512 (weight folding) ----------------
__global__ __launch_bounds__(256) void k_gemm_nn(
    const float* __restrict__ A0, const float* __restrict__ B0, float* __restrict__ O0,
    const float* __restrict__ A1, const float* __restrict__ B1, float* __restrict__ O1) {
  const float* A = blockIdx.z ? A1 : A0;
  const float* B = blockIdx.z ? B1 : B0;
  float* O = blockIdx.z ? O1 : O0;
  __shared__ float As[16][68];
  __shared__ float Bs[16][68];
  const int m0 = blockIdx.y * 64, n0 = blockIdx.x * 64;
  const int tid = threadIdx.x;
  const int tx = tid & 15, ty = tid >> 4;
  const int sr = tid >> 2, skq = (tid & 3) * 4;
  float acc[4][4] = {};
  for (int k0 = 0; k0 < 512; k0 += 16) {
    {
      float4 v = *(const float4*)&A[(long)(m0 + sr) * 512 + k0 + skq];
      As[skq][sr] = v.x; As[skq + 1][sr] = v.y; As[skq + 2][sr] = v.z; As[skq + 3][sr] = v.w;
    }
#pragma unroll
    for (int p = 0; p < 4; ++p) {
      int idx = tid + p * 256;
      int kk = idx >> 6, jj = idx & 63;
      Bs[kk][jj] = B[(long)(k0 + kk) * 512 + n0 + jj];
    }
    __syncthreads();
#pragma unroll
    for (int k = 0; k < 16; ++k) {
      const float4 a = *(const float4*)&As[k][ty * 4];
      const float4 w = *(const float4*)&Bs[k][tx * 4];
      acc[0][0] += a.x * w.x; acc[0][1] += a.x * w.y; acc[0][2] += a.x * w.z; acc[0][3] += a.x * w.w;
      acc[1][0] += a.y * w.x; acc[1][1] += a.y * w.y; acc[1][2] += a.y * w.z; acc[1][3] += a.y * w.w;
      acc[2][0] += a.z * w.x; acc[2][1] += a.z * w.y; acc[2][2] += a.z * w.z; acc[2][3] += a.z * w.w;
      acc[3][0] += a.w * w.x; acc[3][1] += a.w * w.y; acc[3][2] += a.w * w.z; acc[3][3] += a.w * w.w;
    }
    __syncthreads();
  }
#pragma unroll
  for (int i = 0; i < 4; ++i)
#pragma unroll
    for (int j = 0; j < 4; ++j)
      O[(long)(m0 + ty * 4 + i) * 512 + n0 + tx * 4 + j] = acc[i][j];
}

// ---------------- perm: stable sort rows by ilens descending + active counts ----------------
__global__ __launch_bounds__(256) void k_perm(
    const int* __restrict__ ilens, int* __restrict__ perm, int* __restrict__ nact) {
  __shared__ int cnt[9];
  __shared__ int start[9];
  const int tid = threadIdx.x;
  if (tid < 9) cnt[tid] = 0;
  __syncthreads();
  for (int c = tid; c < C_; c += 256) atomicAdd(&cnt[ilens[c]], 1);
  __syncthreads();
  if (tid == 0) {
    int acc = 0;
    for (int k = 8; k >= 0; --k) { start[k] = acc; if (k > 0) acc += cnt[k]; }
    for (int t = 0; t < 8; ++t) nact[t] = start[t];
  }
  __syncthreads();
  const int wave = tid >> 6, lane = tid & 63;
  for (int k = wave + 1; k <= 8; k += 4) {
    int base = start[k];
    for (int c0 = 0; c0 < C_; c0 += 64) {
      int c = c0 + lane;
      bool f = (c < C_) && (ilens[c] == k);
      unsigned long long m = __ballot(f);
      if (f) {
        int r = __popcll(m & ((1ull << lane) - 1ull));
        perm[base + r] = c;
      }
      base += __popcll(m);
    }
  }
}

// ---------------- ctx LSTM recurrent step (fwd compaction, t==0 zero-state) ----------------
__global__ __launch_bounds__(256) void k_ctx_step(
    const float* __restrict__ xz, const int* __restrict__ ctx_idxs,
    const float* __restrict__ Whh_f, const float* __restrict__ Whh_b,
    const float* __restrict__ h_prev, float* __restrict__ h_next,
    float* __restrict__ c_st,
    float* __restrict__ hf_all, float* __restrict__ hb_all,
    const int* __restrict__ perm, const int* __restrict__ nactArr, int t) {
  __shared__ float Hs[32][20];
  __shared__ float Wg[4][32][68];
  __shared__ float zb[4][16][68];
  const int e0 = blockIdx.x * 64;
  const int c0 = blockIdx.y * 16;
  const int dir = blockIdx.z;
  int nact = C_;
  if (dir == 0) {
    nact = nactArr[t];
    if (c0 >= nact) return;
  }
  const int tid = threadIdx.x;
  const float* Whh = dir ? Whh_b : Whh_f;
  const float* hp = h_prev + (size_t)dir * C_ * E_;
  const int gp = tid >> 7;
  const int rem = tid & 127;
  const int cy = rem >> 4;
  const int ex = rem & 15;
  const bool hstage = (tid < 128);
  const int hcr = tid & 15, hkq = ((tid >> 4) & 7) * 4;
  const int hc = c0 + hcr;
  int hrow = -1;
  if (dir == 0) { if (hc < nact) hrow = perm[hc]; }
  else if (hc < C_) hrow = hc;
  const bool loadH = (t > 0);
  float4 acc4[2][2];
  acc4[0][0] = acc4[0][1] = acc4[1][0] = acc4[1][1] = make_float4(0.f, 0.f, 0.f, 0.f);
  float4 phv = make_float4(0.f, 0.f, 0.f, 0.f);
  float4 pwv[8];
  if (hstage && hrow >= 0 && loadH) phv = *(const float4*)&hp[(size_t)hrow * E_ + hkq];
#pragma unroll
  for (int p = 0; p < 8; ++p) {
    int idx = tid + p * 256;
    int ee = idx & 63, kq = ((idx >> 6) & 7) * 4, gg = idx >> 9;
    pwv[p] = *(const float4*)&Whh[(size_t)(gg * E_ + e0 + ee) * E_ + kq];
  }
  for (int k0 = 0; k0 < E_; k0 += 32) {
    if (hstage) {
      Hs[hkq][hcr] = phv.x; Hs[hkq + 1][hcr] = phv.y; Hs[hkq + 2][hcr] = phv.z; Hs[hkq + 3][hcr] = phv.w;
    }
#pragma unroll
    for (int p = 0; p < 8; ++p) {
      int idx = tid + p * 256;
      int ee = idx & 63, kq = ((idx >> 6) & 7) * 4, gg = idx >> 9;
      Wg[gg][kq][ee] = pwv[p].x; Wg[gg][kq + 1][ee] = pwv[p].y; Wg[gg][kq + 2][ee] = pwv[p].z; Wg[gg][kq + 3][ee] = pwv[p].w;
    }
    __syncthreads();
    const int kn = k0 + 32;
    if (kn < E_) {
      phv = make_float4(0.f, 0.f, 0.f, 0.f);
      if (hstage && hrow >= 0 && loadH) phv = *(const float4*)&hp[(size_t)hrow * E_ + kn + hkq];
#pragma unroll
      for (int p = 0; p < 8; ++p) {
        int idx = tid + p * 256;
        int ee = idx & 63, kq = ((idx >> 6) & 7) * 4, gg = idx >> 9;
        pwv[p] = *(const float4*)&Whh[(size_t)(gg * E_ + e0 + ee) * E_ + kn + kq];
      }
    }
#pragma unroll
    for (int kk = 0; kk < 32; ++kk) {
      const float a0 = Hs[kk][cy * 2];
      const float a1 = Hs[kk][cy * 2 + 1];
#pragma unroll
      for (int gg = 0; gg < 2; ++gg) {
        const float4 w = *(const float4*)&Wg[gp * 2 + gg][kk][ex * 4];
        fma4(acc4[gg][0], a0, w);
        fma4(acc4[gg][1], a1, w);
      }
    }
    __syncthreads();
  }
#pragma unroll
  for (int gg = 0; gg < 2; ++gg) {
    *(float4*)&zb[gp * 2 + gg][cy * 2 + 0][ex * 4] = acc4[gg][0];
    *(float4*)&zb[gp * 2 + gg][cy * 2 + 1][ex * 4] = acc4[gg][1];
  }
  __syncthreads();
  const int lpos = dir ? (L_ - 1 - t) : t;
  const float* xz_dir = xz + (size_t)dir * VOC_ * E4_;
  float* c_state = c_st + (size_t)dir * C_ * E_;
  float* hn_out = h_next + (size_t)dir * C_ * E_;
  float* hall = dir ? hb_all : hf_all;
  const int oc = tid >> 4, oe = (tid & 15) * 4;
  const int lc = c0 + oc;
  int c = -1;
  if (dir == 0) { if (lc < nact) c = perm[lc]; }
  else if (lc < C_) c = lc;
  if (c >= 0) {
    const int e = e0 + oe;
    const int tok = ctx_idxs[c * L_ + lpos];
    const float* xr = xz_dir + (size_t)tok * E4_;
    float zi[4], zf[4], zg[4], zo[4], cp[4], cn[4], hn[4];
    *(float4*)zi = *(const float4*)&xr[e];
    *(float4*)zf = *(const float4*)&xr[E_ + e];
    *(float4*)zg = *(const float4*)&xr[2 * E_ + e];
    *(float4*)zo = *(const float4*)&xr[3 * E_ + e];
    if (loadH) *(float4*)cp = *(const float4*)&c_state[(size_t)c * E_ + e];
    else { cp[0] = cp[1] = cp[2] = cp[3] = 0.f; }
#pragma unroll
    for (int j = 0; j < 4; ++j) {
      float vi = zi[j] + zb[0][oc][oe + j];
      float vf = zf[j] + zb[1][oc][oe + j];
      float vg = zg[j] + zb[2][oc][oe + j];
      float vo = zo[j] + zb[3][oc][oe + j];
      cn[j] = fsig(vf) * cp[j] + fsig(vi) * ftanh(vg);
      hn[j] = fsig(vo) * ftanh(cn[j]);
    }
    *(float4*)&c_state[(size_t)c * E_ + e] = *(float4*)cn;
    *(float4*)&hn_out[(size_t)c * E_ + e] = *(float4*)hn;
    *(float4*)&hall[((size_t)c * L_ + lpos) * E_ + e] = *(float4*)hn;
  }
}

// ---------------- masked mean over L of concat(hf,hb) ----------------
__global__ __launch_bounds__(256) void k_ctx_mean(
    const float* __restrict__ hf_all, const float* __restrict__ hb_all,
    const int* __restrict__ ilens, float* __restrict__ cat_mean) {
  int idx = blockIdx.x * 256 + threadIdx.x;
  if (idx >= C_ * 2 * E_) return;
  int c = idx / (2 * E_), e = idx - c * 2 * E_;
  const float* src = (e < E_) ? hf_all : hb_all;
  int ee = e & (E_ - 1);
  int il = ilens[c];
  float s = 0.f;
#pragma unroll
  for (int l = 0; l < L_; ++l)
    if (l < il) s += src[((size_t)c * L_ + l) * E_ + ee];
  cat_mean[idx] = s / (float)il;
}

// ---------------- hist LSTM step v2: 64 blocks x 256 thr ----------------
__global__ __launch_bounds__(256) void k_hist_step2(
    const float* __restrict__ xproj, const float* __restrict__ Whh,
    const float* __restrict__ hprev, float* __restrict__ hcur,
    float* __restrict__ cstG, float* __restrict__ hall, int u) {
  __shared__ float Wl[32][516];
  __shared__ float hb[8][520];
  const int tid = threadIdx.x;
  const int e0 = blockIdx.x * 8;
  {
    int lr = tid >> 3, part = tid & 7;
    int g2 = lr >> 3, e2 = lr & 7;
    const float* src = Whh + (size_t)(g2 * D_ + e0 + e2) * D_;
#pragma unroll
    for (int i = 0; i < 16; ++i) {
      int k4 = part + i * 8;
      *(float4*)&Wl[lr][k4 * 4] = *(const float4*)&src[k4 * 4];
    }
  }
  {
    int b2 = tid >> 5, part = tid & 31;
#pragma unroll
    for (int i = 0; i < 4; ++i) {
      int k4 = part + i * 32;
      float4 v = make_float4(0.f, 0.f, 0.f, 0.f);
      if (u > 0) v = *(const float4*)&hprev[(size_t)b2 * D_ + k4 * 4];
      *(float4*)&hb[b2][k4 * 4] = v;
    }
  }
  __syncthreads();
  const int b = tid >> 5, g = (tid >> 3) & 3, e = tid & 7;
  const int lr = tid & 31;
  float dot = 0.f;
#pragma unroll 8
  for (int k4 = 0; k4 < 128; ++k4) {
    float4 w = *(const float4*)&Wl[lr][k4 * 4];
    float4 h4 = *(const float4*)&hb[b][k4 * 4];
    dot += w.x * h4.x + w.y * h4.y + w.z * h4.z + w.w * h4.w;
  }
  float z = dot + xproj[((size_t)b * U_ + u) * D4_ + g * D_ + e0 + e];
  const int l = tid & 63;
  const int base = (l & 32) | e;
  float zi = __shfl(z, base, 64);
  float zf = __shfl(z, base + 8, 64);
  float zg = __shfl(z, base + 16, 64);
  float zo = __shfl(z, base + 24, 64);
  if (g == 0) {
    float cp = (u > 0) ? cstG[(size_t)b * D_ + e0 + e] : 0.f;
    float cn = fsig(zf) * cp + fsig(zi) * ftanh(zg);
    cstG[(size_t)b * D_ + e0 + e] = cn;
    float hv = fsig(zo) * ftanh(cn);
    hcur[(size_t)b * D_ + e0 + e] = hv;
    hall[((size_t)b * U_ + u) * D_ + e0 + e] = hv;
  }
}

// ---------------- row-wise exp: Sm->EM / Sh->EH in place (+ head-sums) ----------------
__global__ __launch_bounds__(256) void k_rowexp(
    float* __restrict__ Sm, float* __restrict__ Sh,
    float* __restrict__ SmS, float* __restrict__ ShS) {
  int row = blockIdx.x;
  float* base; float* sumo;
  if (row < B_ * T_) { base = Sm + (size_t)row * HC_; sumo = SmS + (size_t)row * C_; }
  else { int r2 = row - B_ * T_; base = Sh + (size_t)r2 * HC_; sumo = ShS + (size_t)r2 * C_; }
  int tid = threadIdx.x;
  for (int c = tid; c < C_; c += 256) {
    float s = base[c] + base[C_ + c] + base[2 * C_ + c] + base[3 * C_ + c];
    sumo[c] = 0.25f * s;
  }
  __syncthreads();
  int h = tid >> 6, lane = tid & 63;
  float* p = base + (size_t)h * C_;
  float mx = -1e30f;
  for (int c = lane; c < C_; c += 64) mx = fmaxf(mx, p[c]);
#pragma unroll
  for (int o = 32; o; o >>= 1) mx = fmaxf(mx, __shfl_xor(mx, o));
  for (int c = lane; c < C_; c += 64) p[c] = __expf(p[c] - mx);
}

// ---------------- prob/logit streaming writes + den (fused) + decode bits ----------------
__global__ __launch_bounds__(256) void k_plw(
    const float* __restrict__ EM, const float* __restrict__ EH,
    const float* __restrict__ SmS, const float* __restrict__ ShS,
    const int* __restrict__ hidx,
    float* __restrict__ den, float* __restrict__ prob, float* __restrict__ logit,
    unsigned char* __restrict__ bits) {
  __shared__ float sEM[H_][1008];
  __shared__ float sSS[1000];
  __shared__ float sB[4], sT[4];
  __shared__ float sW[4][4];
  __shared__ float sInvU[4];
  const int bt = blockIdx.x >> 2;
  const int ug = blockIdx.x & 3;
  const int b = bt >> 7;
  const int tid = threadIdx.x;
  for (int i = tid; i < H_ * C_; i += 256) sEM[i / C_][i % C_] = EM[(size_t)bt * HC_ + i];
  for (int c = tid; c < C_; c += 256) sSS[c] = SmS[(size_t)bt * C_ + c];
  __syncthreads();
#pragma unroll
  for (int j = 0; j < 4; ++j) {
    const int u = ug * 4 + j;
    const int valid = (u + 1 < U_ - 1) ? (u + 1) : (U_ - 1);
    const int tok = hidx[b * U_ + valid];
    const float* eh0 = EH + ((size_t)b * U_ + u) * HC_;
    float d0 = 0.f, d1 = 0.f, d2 = 0.f, d3 = 0.f;
    for (int c = tid; c < C_; c += 256) {
      d0 += sEM[0][c] * eh0[c];
      d1 += sEM[1][c] * eh0[C_ + c];
      d2 += sEM[2][c] * eh0[2 * C_ + c];
      d3 += sEM[3][c] * eh0[3 * C_ + c];
    }
#pragma unroll
    for (int o = 32; o; o >>= 1) {
      d0 += __shfl_xor(d0, o); d1 += __shfl_xor(d1, o);
      d2 += __shfl_xor(d2, o); d3 += __shfl_xor(d3, o);
    }
    const int wv = tid >> 6;
    if ((tid & 63) == 0) { sW[wv][0] = d0; sW[wv][1] = d1; sW[wv][2] = d2; sW[wv][3] = d3; }
    __syncthreads();
    if (tid < 4) {
      float dd = sW[0][tid] + sW[1][tid] + sW[2][tid] + sW[3][tid];
      den[((size_t)bt * U_ + u) * H_ + tid] = dd;
      sInvU[tid] = 0.25f / dd;
    }
    __syncthreads();
    const float i0 = sInvU[0], i1 = sInvU[1], i2 = sInvU[2], i3 = sInvU[3];
    const float* shs = ShS + ((size_t)b * U_ + u) * C_;
    size_t obase = ((size_t)bt * U_ + u) * C_;
    for (int c = tid; c < C_; c += 256) {
      float pr = sEM[0][c] * eh0[c] * i0 + sEM[1][c] * eh0[C_ + c] * i1
               + sEM[2][c] * eh0[2 * C_ + c] * i2 + sEM[3][c] * eh0[3 * C_ + c] * i3;
      __builtin_nontemporal_store(pr, &prob[obase + c]);
      __builtin_nontemporal_store(sSS[c] + shs[c], &logit[obase + c]);
      if (c == 0) sB[j] = pr;
      if (c == tok) sT[j] = pr;
    }
    __syncthreads();
  }
  if (tid < 4) bits[bt * U_ + ug * 4 + tid] = (sT[tid] > sB[tid]) ? 1 : 0;
}

// ---------------- decode scan ----------------
__global__ __launch_bounds__(64) void k_scan(
    const unsigned char* __restrict__ bits, int* __restrict__ u_sel) {
  __shared__ unsigned char sb[B_ * T_ * U_];
  int tid = threadIdx.x;
  for (int i = tid; i < B_ * T_ * U_; i += 64) sb[i] = bits[i];
  __syncthreads();
  if (tid < B_) {
    int u = 0;
    for (int t = 0; t < T_; ++t) {
      int uc = (u < U_ - 1) ? u : (U_ - 1);
      u_sel[tid * T_ + t] = uc;
      u = uc + (int)sb[(tid * T_ + t) * U_ + uc];
    }
  }
}

// ---------------- PV on SELECTED rows, split-c partials ----------------
__global__ __launch_bounds__(256) void k_pvg2(
    const float* __restrict__ EM, const float* __restrict__ EH,
    const float* __restrict__ den, const int* __restrict__ u_sel,
    const float* __restrict__ vmat, float* __restrict__ pvp) {
  constexpr int KC = 64;
  __shared__ float wS[2][4][4][KC + 4];
  __shared__ float invS[8][4];
  __shared__ int bS[8], tS[8], uS[8];
  const int tid = threadIdx.x;
  const int cblk = blockIdx.y;
  if (tid < 32) {
    int g8 = tid >> 2, hh = tid & 3;
    int bt = blockIdx.x * 8 + g8;
    int b = bt >> 7, t = bt & 127;
    int u = u_sel[bt];
    if (hh == 0) { bS[g8] = b; tS[g8] = t; uS[g8] = u; }
    invS[g8][hh] = 1.f / den[((size_t)bt * U_ + u) * H_ + hh];
  }
  __syncthreads();
  const int sub = tid >> 7, lt = tid & 127;
  const int d = lt * 4;
  const int h = lt >> 5;
  float4 acc[4];
  acc[0] = acc[1] = acc[2] = acc[3] = make_float4(0.f, 0.f, 0.f, 0.f);
  const int cbeg = cblk * 128;
  const int cend = (cbeg + 128 < C_) ? (cbeg + 128) : C_;
  for (int c0 = cbeg; c0 < cend; c0 += KC) {
#pragma unroll
    for (int p = 0; p < 8; ++p) {
      int idx = tid + p * 256;
      int cc = idx & 63;
      int rest = idx >> 6;
      int hh = rest & 3, gg = (rest >> 2) & 3, ss = rest >> 4;
      int g8 = ss * 4 + gg;
      int c = c0 + cc;
      float w = 0.f;
      if (c < C_) {
        int b = bS[g8], t = tS[g8], u = uS[g8];
        float em = EM[(((size_t)b * T_ + t) * H_ + hh) * C_ + c];
        float eh = EH[(((size_t)b * U_ + u) * H_ + hh) * C_ + c];
        w = em * eh * invS[g8][hh];
      }
      wS[ss][gg][hh][cc] = w;
    }
    __syncthreads();
#pragma unroll 4
    for (int q = 0; q < KC / 4; ++q) {
      const float4 w0 = *(const float4*)&wS[sub][0][h][q * 4];
      const float4 w1 = *(const float4*)&wS[sub][1][h][q * 4];
      const float4 w2 = *(const float4*)&wS[sub][2][h][q * 4];
      const float4 w3 = *(const float4*)&wS[sub][3][h][q * 4];
      int c = c0 + q * 4;
      float4 v;
      if (c < C_) { v = *(const float4*)&vmat[(size_t)c * D_ + d];
        fma4(acc[0], w0.x, v); fma4(acc[1], w1.x, v); fma4(acc[2], w2.x, v); fma4(acc[3], w3.x, v); }
      if (c + 1 < C_) { v = *(const float4*)&vmat[(size_t)(c + 1) * D_ + d];
        fma4(acc[0], w0.y, v); fma4(acc[1], w1.y, v); fma4(acc[2], w2.y, v); fma4(acc[3], w3.y, v); }
      if (c + 2 < C_) { v = *(const float4*)&vmat[(size_t)(c + 2) * D_ + d];
        fma4(acc[0], w0.z, v); fma4(acc[1], w1.z, v); fma4(acc[2], w2.z, v); fma4(acc[3], w3.z, v); }
      if (c + 3 < C_) { v = *(const float4*)&vmat[(size_t)(c + 3) * D_ + d];
        fma4(acc[0], w0.w, v); fma4(acc[1], w1.w, v); fma4(acc[2], w2.w, v); fma4(acc[3], w3.w, v); }
    }
    __syncthreads();
  }
  float* pout = pvp + (size_t)cblk * PVSLAB;
#pragma unroll
  for (int g = 0; g < 4; ++g) {
    int bt = (bS[sub * 4 + g] << 7) + tS[sub * 4 + g];
    *(float4*)&pout[(size_t)bt * D_ + d] = acc[g];
  }
}

// ---------------- host launch ----------------
extern "C" void kernel_launch(void* const* d_in, const int* in_sizes, int n_in,
                              void* d_out, int out_size, void* d_ws, size_t ws_size,
                              hipStream_t stream) {
  const float* model_embed = (const float*)d_in[0];
  const float* emb_table   = (const float*)d_in[1];
  const float* Wih_f = (const float*)d_in[2];
  const float* Whh_f = (const float*)d_in[3];
  const float* b_f   = (const float*)d_in[4];
  const float* Wih_b = (const float*)d_in[5];
  const float* Whh_b = (const float*)d_in[6];
  const float* b_b   = (const float*)d_in[7];
  const float* ctx_out_W  = (const float*)d_in[8];
  const float* hist_Wih   = (const float*)d_in[9];
  const float* hist_Whh   = (const float*)d_in[10];
  const float* hist_b     = (const float*)d_in[11];
  const float* hist_out_W = (const float*)d_in[12];
  const float* Wq = (const float*)d_in[13];
  const float* Wk = (const float*)d_in[14];
  const float* Wv = (const float*)d_in[15];
  const float* Wo = (const float*)d_in[16];
  const float* acoustic_W = (const float*)d_in[17];
  const int* ctx_idxs = (const int*)d_in[18];
  const int* hidx     = (const int*)d_in[19];
  const int* ilens    = (const int*)d_in[20];

  if (ws_size < WS_NEED * sizeof(float)) return;

  float* ws = (float*)d_ws;
  float* o_out     = (float*)d_out;
  float* logit_out = o_out + (size_t)B_ * T_ * D_;
  float* prob_out  = logit_out + (size_t)B_ * T_ * U_ * C_;

  // ---- perm for fwd dead-row elimination ----
  k_perm<<<dim3(1), 256, 0, stream>>>(ilens, (int*)(ws + PERM_), (int*)(ws + NACT_));

  // ---- weight folding ----
  k_gemm_nn<<<dim3(8, 8, 2), 256, 0, stream>>>(
      Wq, acoustic_W, ws + WQA, Wq, hist_out_W, ws + WQH);

  // ---- ctx LSTM input projections, whole vocab, both dirs ----
  {
    GemmP pf{};
    pf.A1 = emb_table; pf.lda1 = E_;
    pf.W1 = Wih_f; pf.ldw1 = E_;
    pf.bias = b_f;
    pf.out = ws + XZ_; pf.ldc = E4_;
    pf.M = VOC_; pf.N = E4_; pf.K = E_; pf.scale = 1.f;
    GemmP pb = pf;
    pb.W1 = Wih_b; pb.bias = b_b; pb.out = ws + XZ_ + (size_t)VOC_ * E4_;
    k_gemm64xcd<<<dim3(XZ_NWG, 1, 2), 256, 0, stream>>>(pf, pb);
  }

  // ---- ctx LSTM recurrence: 8 per-step launches (fwd compacted, t0 zero-state) ----
  for (int t = 0; t < L_; ++t) {
    float* hp = ws + ((t & 1) ? HPONG : HPING);
    float* hn = ws + ((t & 1) ? HPING : HPONG);
    k_ctx_step<<<dim3(4, (C_ + 15) / 16, 2), 256, 0, stream>>>(
        ws + XZ_, ctx_idxs, Whh_f, Whh_b, hp, hn, ws + CST,
        ws + HFALL, ws + HBALL,
        (const int*)(ws + PERM_), (const int*)(ws + NACT_), t);
  }

  // ---- masked mean + ctx_out projection ----
  k_ctx_mean<<<dim3((C_ * 2 * E_ + 255) / 256), 256, 0, stream>>>(
      ws + HFALL, ws + HBALL, ilens, ws + CATM);
  {
    GemmP p{};
    p.A1 = ws + CATM; p.lda1 = 2 * E_;
    p.W1 = ctx_out_W; p.ldw1 = 2 * E_;
    p.out = ws + CTXM; p.ldc = D_; p.M = C_; p.N = D_; p.K = 2 * E_; p.scale = 1.f;
    k_gemm64<<<dim3(8, 16, 1), 256, 0, stream>>>(p);
  }

  // ---- k (scaled), v, hist input projection, qm — one launch ----
  {
    GemmP pk{};
    pk.A1 = ws + CTXM; pk.lda1 = D_;
    pk.W1 = Wk; pk.ldw1 = D_;
    pk.out = ws + KWS; pk.ldc = D_; pk.M = C_; pk.N = D_; pk.K = D_; pk.scale = SCALE_;
    GemmP pv = pk;
    pv.W1 = Wv; pv.out = ws + VWS; pv.scale = 1.f;
    GemmP ph{};
    ph.A1 = ws + CTXM; ph.lda1 = D_;
    ph.ridx = hidx; ph.ridx_stride = 1; ph.ridx_off = 0;
    ph.W1 = hist_Wih; ph.ldw1 = D_;
    ph.bias = hist_b;
    ph.out = ws + HXP; ph.ldc = D4_; ph.M = B_ * U_; ph.N = D4_; ph.K = D_; ph.scale = 1.f;
    GemmP pm{};
    pm.A1 = model_embed; pm.lda1 = D_;
    pm.W1 = ws + WQA; pm.ldw1 = D_;
    pm.out = ws + QM_; pm.ldc = D_; pm.M = B_ * T_; pm.N = D_; pm.K = D_; pm.scale = 1.f;
    k_gemm64x4<<<dim3(32, 16, 4), 256, 0, stream>>>(pk, pv, ph, pm);
  }

  // ---- hist LSTM recurrence: 16 per-step launches ----
  for (int u = 0; u < U_; ++u) {
    const float* hp = ws + ((u & 1) ? HG2 : HGLOB);
    float* hc = ws + ((u & 1) ? HGLOB : HG2);
    k_hist_step2<<<dim3(64), 256, 0, stream>>>(
        ws + HXP, hist_Whh, hp, hc, ws + HISTC, ws + HALL, u);
  }

  // ---- qh ----
  {
    GemmP ph{};
    ph.A1 = ws + HALL; ph.lda1 = D_;
    ph.W1 = ws + WQH; ph.ldw1 = D_;
    ph.out = ws + QH_; ph.ldc = D_; ph.M = B_ * U_; ph.N = D_; ph.K = D_; ph.scale = 1.f;
    k_gemm64<<<dim3(8, 2, 1), 256, 0, stream>>>(ph);
  }

  // ---- Sm, Sh (per-head via z, pipelined 128-core) ----
  {
    GemmP pm{};
    pm.A1 = ws + QM_; pm.lda1 = D_;
    pm.W1 = ws + KWS; pm.ldw1 = D_;
    pm.out = ws + SM_; pm.ldc = HC_; pm.M = B_ * T_; pm.N = C_; pm.K = DH_; pm.scale = 1.f;
    pm.a_zoff = DH_; pm.w_zoff = DH_; pm.c_zoff = C_;
    GemmP ph = pm;
    ph.A1 = ws + QH_; ph.out = ws + SH_; ph.M = B_ * U_;
    k_gemm128x2<<<dim3(8, 16, 8), 256, 0, stream>>>(pm, ph, 4);
  }

  // ---- exp factorization ----
  k_rowexp<<<dim3(B_ * T_ + B_ * U_), 256, 0, stream>>>(
      ws + SM_, ws + SH_, ws + SMSUM, ws + SHSUM);

  // ---- prob/logit streaming writes + fused den + bits ----
  k_plw<<<dim3(B_ * T_ * 4), 256, 0, stream>>>(
      ws + SM_, ws + SH_, ws + SMSUM, ws + SHSUM, hidx,
      ws + DEN_, prob_out, logit_out, (unsigned char*)(ws + BITS_));

  // ---- decode scan ----
  k_scan<<<dim3(1), 64, 0, stream>>>((const unsigned char*)(ws + BITS_), (int*)(ws + USEL_));

  // ---- PV on selected rows (split-c) ----
  k_pvg2<<<dim3(128, 8), 256, 0, stream>>>(
      ws + SM_, ws + SH_, ws + DEN_, (const int*)(ws + USEL_), ws + VWS, ws + PVP_);

  // ---- Wo projection with fused 8-slab reduce -> o ----
  k_wo_red8<<<dim3(8, 16), 256, 0, stream>>>(ws + PVP_, Wo, o_out);
}

// Round 18
// 754.730 us; speedup vs baseline: 1.0571x; 1.0571x over previous
//
#include <hip/hip_runtime.h>
#include <math.h>

// ---------------- compile-time sizes ----------------
namespace {
constexpr int B_ = 8, T_ = 128, D_ = 512, C_ = 1000, L_ = 8, U_ = 16, E_ = 256, H_ = 4;
constexpr int VOC_ = 5000;
constexpr int DH_ = D_ / H_;      // 128
constexpr int E4_ = 4 * E_;       // 1024
constexpr int D4_ = 4 * D_;       // 2048
constexpr int TU_ = T_ * U_;      // 2048
constexpr int HC_ = H_ * C_;      // 4000
constexpr float SCALE_ = 0.088388347648318447f; // 1/sqrt(128)

// XZ swizzle geometry
constexpr int XZ_NB  = E4_ / 64;            // 16 n-tiles (fastest)
constexpr int XZ_MB  = (VOC_ + 63) / 64;    // 79 m-tiles
constexpr int XZ_NWG = XZ_NB * XZ_MB;       // 1264
constexpr int XZ_CPX = XZ_NWG / 8;          // 158 per XCD

// ---------------- ws layout (float offsets) ----------------
constexpr size_t XZ_    = 0;
constexpr size_t SM_    = 0;                                   // B*T*H*C
constexpr size_t SH_    = SM_ + (size_t)B_ * T_ * HC_;         // B*U*H*C
constexpr size_t AOUT_  = SH_ + (size_t)B_ * U_ * HC_;         // B*T*D
constexpr size_t PVP_   = AOUT_ + (size_t)B_ * T_ * D_;        // 8*1024*512 partials
constexpr size_t REG_A  = 2ul * VOC_ * E4_;
constexpr size_t HPING  = REG_A;                               // 2*C*E
constexpr size_t CST    = HPING + 2ul * C_ * E_;               // 2*C*E
constexpr size_t HPONG  = CST + 2ul * C_ * E_;
constexpr size_t HFALL  = HPONG + 2ul * C_ * E_;               // C*L*E
constexpr size_t HBALL  = HFALL + (size_t)C_ * L_ * E_;
constexpr size_t CATM   = HBALL + (size_t)C_ * L_ * E_;        // C*2E
constexpr size_t CTXM   = CATM + (size_t)C_ * 2 * E_;          // C*D
constexpr size_t KWS    = CTXM + (size_t)C_ * D_;
constexpr size_t VWS    = KWS + (size_t)C_ * D_;
constexpr size_t WQA    = VWS + (size_t)C_ * D_;               // D*D
constexpr size_t WQH    = WQA + (size_t)D_ * D_;               // D*D
constexpr size_t HXP    = WQH + (size_t)D_ * D_;               // B*U*4D
constexpr size_t HALL   = HXP + (size_t)B_ * U_ * D4_;         // B*U*D
constexpr size_t HGLOB  = HALL + (size_t)B_ * U_ * D_;         // B*D (h ping)
constexpr size_t HG2    = HGLOB + (size_t)B_ * D_;             // B*D (h pong)
constexpr size_t HISTC  = HG2 + (size_t)B_ * D_;               // B*D (c state)
constexpr size_t QM_    = HISTC + (size_t)B_ * D_;             // B*T*D
constexpr size_t QH_    = QM_ + (size_t)B_ * T_ * D_;          // B*U*D
constexpr size_t SMSUM  = QH_ + (size_t)B_ * U_ * D_;          // B*T*C
constexpr size_t SHSUM  = SMSUM + (size_t)B_ * T_ * C_;        // B*U*C
constexpr size_t DEN_   = SHSUM + (size_t)B_ * U_ * C_;        // B*T*U*H
constexpr size_t BITS_  = DEN_ + (size_t)B_ * T_ * U_ * H_;    // 16384 B
constexpr size_t USEL_  = BITS_ + 4096;
constexpr size_t PERM_  = USEL_ + (size_t)B_ * T_;             // C ints
constexpr size_t NACT_  = PERM_ + C_;                          // 8 ints
constexpr size_t WS_NEED = NACT_ + 8;
constexpr size_t PVSLAB = (size_t)B_ * T_ * D_;                // 524288
} // namespace

__device__ __forceinline__ float fsig(float x)  { return 1.f / (1.f + __expf(-x)); }
__device__ __forceinline__ float ftanh(float x) { return 1.f - 2.f / (__expf(2.f * x) + 1.f); }
__device__ __forceinline__ void fma4(float4& a, float w, const float4& v) {
  a.x += w * v.x; a.y += w * v.y; a.z += w * v.z; a.w += w * v.w;
}

// ---------------- generic NT GEMM (X @ W^T), 64 x TN tile, reg-prefetch pipeline ----------------
struct GemmP {
  const float* A1; int lda1;
  const int* ridx; int ridx_stride; int ridx_off;
  const float* W1; int ldw1;
  const float* bias;
  float* out; int ldc;
  int M, N, K;
  float scale;
  int a_zoff, w_zoff, c_zoff;
};

template <int TN>
__device__ __forceinline__ void gemm_core(const GemmP& g, int z, int by, int bx) {
  constexpr int UN = TN / 16;
  constexpr int WP = TN / 64;
  __shared__ float As[16][68];
  __shared__ float Ws[16][TN + 4];
  const int m0 = by * 64;
  const int n0 = bx * TN;
  if (m0 >= g.M || n0 >= g.N) return;
  const float* A1 = g.A1 + (long)z * g.a_zoff;
  const float* W1 = g.W1 + (long)z * g.w_zoff;
  float* out = g.out + (long)z * g.c_zoff;
  const int tid = threadIdx.x;
  const int tx = tid & 15, ty = tid >> 4;
  const int sr = tid >> 2, skq = (tid & 3) * 4;
  float acc[4][UN] = {};
  int sarow = -1;
  {
    const int gm = m0 + sr;
    if (gm < g.M) sarow = g.ridx ? g.ridx[gm * g.ridx_stride + g.ridx_off] : gm;
  }
  float4 pa, pw[WP];
  {
    pa = make_float4(0.f, 0.f, 0.f, 0.f);
    if (sarow >= 0) pa = *(const float4*)&A1[(long)sarow * g.lda1 + skq];
#pragma unroll
    for (int p = 0; p < WP; ++p) {
      const int gn = n0 + sr + p * 64;
      pw[p] = make_float4(0.f, 0.f, 0.f, 0.f);
      if (gn < g.N) pw[p] = *(const float4*)&W1[(long)gn * g.ldw1 + skq];
    }
  }
  for (int k0 = 0; k0 < g.K; k0 += 16) {
    As[skq][sr] = pa.x; As[skq + 1][sr] = pa.y; As[skq + 2][sr] = pa.z; As[skq + 3][sr] = pa.w;
#pragma unroll
    for (int p = 0; p < WP; ++p) {
      const int r = sr + p * 64;
      Ws[skq][r] = pw[p].x; Ws[skq + 1][r] = pw[p].y; Ws[skq + 2][r] = pw[p].z; Ws[skq + 3][r] = pw[p].w;
    }
    __syncthreads();
    const int kn = k0 + 16;
    if (kn < g.K) {
      pa = make_float4(0.f, 0.f, 0.f, 0.f);
      if (sarow >= 0) pa = *(const float4*)&A1[(long)sarow * g.lda1 + kn + skq];
#pragma unroll
      for (int p = 0; p < WP; ++p) {
        const int gn = n0 + sr + p * 64;
        pw[p] = make_float4(0.f, 0.f, 0.f, 0.f);
        if (gn < g.N) pw[p] = *(const float4*)&W1[(long)gn * g.ldw1 + kn + skq];
      }
    }
#pragma unroll
    for (int k = 0; k < 16; ++k) {
      const float4 a = *(const float4*)&As[k][ty * 4];
#pragma unroll
      for (int q = 0; q < UN / 4; ++q) {
        const float4 w = *(const float4*)&Ws[k][q * 64 + tx * 4];
        acc[0][q*4+0] += a.x * w.x; acc[0][q*4+1] += a.x * w.y; acc[0][q*4+2] += a.x * w.z; acc[0][q*4+3] += a.x * w.w;
        acc[1][q*4+0] += a.y * w.x; acc[1][q*4+1] += a.y * w.y; acc[1][q*4+2] += a.y * w.z; acc[1][q*4+3] += a.y * w.w;
        acc[2][q*4+0] += a.z * w.x; acc[2][q*4+1] += a.z * w.y; acc[2][q*4+2] += a.z * w.z; acc[2][q*4+3] += a.z * w.w;
        acc[3][q*4+0] += a.w * w.x; acc[3][q*4+1] += a.w * w.y; acc[3][q*4+2] += a.w * w.z; acc[3][q*4+3] += a.w * w.w;
      }
    }
    __syncthreads();
  }
#pragma unroll
  for (int i = 0; i < 4; ++i) {
    const int gm = m0 + ty * 4 + i;
    if (gm >= g.M) continue;
#pragma unroll
    for (int q = 0; q < UN / 4; ++q) {
#pragma unroll
      for (int j = 0; j < 4; ++j) {
        const int gn = n0 + q * 64 + tx * 4 + j;
        if (gn >= g.N) continue;
        float v2 = acc[i][q*4+j];
        if (g.bias) v2 += g.bias[gn];
        out[(long)gm * g.ldc + gn] = v2 * g.scale;
      }
    }
  }
}

__global__ __launch_bounds__(256) void k_gemm64(GemmP p)  { gemm_core<64>(p, blockIdx.z, blockIdx.y, blockIdx.x); }
__global__ __launch_bounds__(256) void k_gemm64x2(GemmP p0, GemmP p1, int zs) {
  int z = blockIdx.z;
  if (z < zs) gemm_core<64>(p0, z, blockIdx.y, blockIdx.x);
  else gemm_core<64>(p1, z - zs, blockIdx.y, blockIdx.x);
}
__global__ __launch_bounds__(256) void k_gemm64x3(GemmP p0, GemmP p1, GemmP p2) {
  int z = blockIdx.z;
  if (z == 0) gemm_core<64>(p0, 0, blockIdx.y, blockIdx.x);
  else if (z == 1) gemm_core<64>(p1, 0, blockIdx.y, blockIdx.x);
  else gemm_core<64>(p2, 0, blockIdx.y, blockIdx.x);
}
__global__ __launch_bounds__(256) void k_gemm128x2(GemmP p0, GemmP p1, int zs) {
  int z = blockIdx.z;
  if (z < zs) gemm_core<128>(p0, z, blockIdx.y, blockIdx.x);
  else gemm_core<128>(p1, z - zs, blockIdx.y, blockIdx.x);
}
__global__ __launch_bounds__(256) void k_gemm64xcd(GemmP p0, GemmP p1) {
  const int bid = blockIdx.x;
  const int logical = (bid & 7) * XZ_CPX + (bid >> 3);
  const int bx = logical % XZ_NB;
  const int by = logical / XZ_NB;
  if (blockIdx.z == 0) gemm_core<64>(p0, 0, by, bx);
  else gemm_core<64>(p1, 0, by, bx);
}

// ---------------- NN GEMM: O = A @ B, 512x512x512 (weight folding) ----------------
__global__ __launch_bounds__(256) void k_gemm_nn(
    const float* __restrict__ A0, const float* __restrict__ B0, float* __restrict__ O0,
    const float* __restrict__ A1, const float* __restrict__ B1, float* __restrict__ O1) {
  const float* A = blockIdx.z ? A1 : A0;
  const float* B = blockIdx.z ? B1 : B0;
  float* O = blockIdx.z ? O1 : O0;
  __shared__ float As[16][68];
  __shared__ float Bs[16][68];
  const int m0 = blockIdx.y * 64, n0 = blockIdx.x * 64;
  const int tid = threadIdx.x;
  const int tx = tid & 15, ty = tid >> 4;
  const int sr = tid >> 2, skq = (tid & 3) * 4;
  float acc[4][4] = {};
  for (int k0 = 0; k0 < 512; k0 += 16) {
    {
      float4 v = *(const float4*)&A[(long)(m0 + sr) * 512 + k0 + skq];
      As[skq][sr] = v.x; As[skq + 1][sr] = v.y; As[skq + 2][sr] = v.z; As[skq + 3][sr] = v.w;
    }
#pragma unroll
    for (int p = 0; p < 4; ++p) {
      int idx = tid + p * 256;
      int kk = idx >> 6, jj = idx & 63;
      Bs[kk][jj] = B[(long)(k0 + kk) * 512 + n0 + jj];
    }
    __syncthreads();
#pragma unroll
    for (int k = 0; k < 16; ++k) {
      const float4 a = *(const float4*)&As[k][ty * 4];
      const float4 w = *(const float4*)&Bs[k][tx * 4];
      acc[0][0] += a.x * w.x; acc[0][1] += a.x * w.y; acc[0][2] += a.x * w.z; acc[0][3] += a.x * w.w;
      acc[1][0] += a.y * w.x; acc[1][1] += a.y * w.y; acc[1][2] += a.y * w.z; acc[1][3] += a.y * w.w;
      acc[2][0] += a.z * w.x; acc[2][1] += a.z * w.y; acc[2][2] += a.z * w.z; acc[2][3] += a.z * w.w;
      acc[3][0] += a.w * w.x; acc[3][1] += a.w * w.y; acc[3][2] += a.w * w.z; acc[3][3] += a.w * w.w;
    }
    __syncthreads();
  }
#pragma unroll
  for (int i = 0; i < 4; ++i)
#pragma unroll
    for (int j = 0; j < 4; ++j)
      O[(long)(m0 + ty * 4 + i) * 512 + n0 + tx * 4 + j] = acc[i][j];
}

// ---------------- perm: stable sort rows by ilens descending + active counts ----------------
__global__ __launch_bounds__(256) void k_perm(
    const int* __restrict__ ilens, int* __restrict__ perm, int* __restrict__ nact) {
  __shared__ int cnt[9];
  __shared__ int start[9];
  const int tid = threadIdx.x;
  if (tid < 9) cnt[tid] = 0;
  __syncthreads();
  for (int c = tid; c < C_; c += 256) atomicAdd(&cnt[ilens[c]], 1);
  __syncthreads();
  if (tid == 0) {
    int acc = 0;
    for (int k = 8; k >= 0; --k) { start[k] = acc; if (k > 0) acc += cnt[k]; }
    for (int t = 0; t < 8; ++t) nact[t] = start[t];
  }
  __syncthreads();
  const int wave = tid >> 6, lane = tid & 63;
  for (int k = wave + 1; k <= 8; k += 4) {
    int base = start[k];
    for (int c0 = 0; c0 < C_; c0 += 64) {
      int c = c0 + lane;
      bool f = (c < C_) && (ilens[c] == k);
      unsigned long long m = __ballot(f);
      if (f) {
        int r = __popcll(m & ((1ull << lane) - 1ull));
        perm[base + r] = c;
      }
      base += __popcll(m);
    }
  }
}

// ---------------- ctx LSTM recurrent step (fwd compaction, t==0 zero-state) ----------------
__global__ __launch_bounds__(256) void k_ctx_step(
    const float* __restrict__ xz, const int* __restrict__ ctx_idxs,
    const float* __restrict__ Whh_f, const float* __restrict__ Whh_b,
    const float* __restrict__ h_prev, float* __restrict__ h_next,
    float* __restrict__ c_st,
    float* __restrict__ hf_all, float* __restrict__ hb_all,
    const int* __restrict__ perm, const int* __restrict__ nactArr, int t) {
  __shared__ float Hs[32][20];
  __shared__ float Wg[4][32][68];
  __shared__ float zb[4][16][68];
  const int e0 = blockIdx.x * 64;
  const int c0 = blockIdx.y * 16;
  const int dir = blockIdx.z;
  int nact = C_;
  if (dir == 0) {
    nact = nactArr[t];
    if (c0 >= nact) return;
  }
  const int tid = threadIdx.x;
  const float* Whh = dir ? Whh_b : Whh_f;
  const float* hp = h_prev + (size_t)dir * C_ * E_;
  const int gp = tid >> 7;
  const int rem = tid & 127;
  const int cy = rem >> 4;
  const int ex = rem & 15;
  const bool hstage = (tid < 128);
  const int hcr = tid & 15, hkq = ((tid >> 4) & 7) * 4;
  const int hc = c0 + hcr;
  int hrow = -1;
  if (dir == 0) { if (hc < nact) hrow = perm[hc]; }
  else if (hc < C_) hrow = hc;
  const bool loadH = (t > 0);
  float4 acc4[2][2];
  acc4[0][0] = acc4[0][1] = acc4[1][0] = acc4[1][1] = make_float4(0.f, 0.f, 0.f, 0.f);
  float4 phv = make_float4(0.f, 0.f, 0.f, 0.f);
  float4 pwv[8];
  if (hstage && hrow >= 0 && loadH) phv = *(const float4*)&hp[(size_t)hrow * E_ + hkq];
#pragma unroll
  for (int p = 0; p < 8; ++p) {
    int idx = tid + p * 256;
    int ee = idx & 63, kq = ((idx >> 6) & 7) * 4, gg = idx >> 9;
    pwv[p] = *(const float4*)&Whh[(size_t)(gg * E_ + e0 + ee) * E_ + kq];
  }
  for (int k0 = 0; k0 < E_; k0 += 32) {
    if (hstage) {
      Hs[hkq][hcr] = phv.x; Hs[hkq + 1][hcr] = phv.y; Hs[hkq + 2][hcr] = phv.z; Hs[hkq + 3][hcr] = phv.w;
    }
#pragma unroll
    for (int p = 0; p < 8; ++p) {
      int idx = tid + p * 256;
      int ee = idx & 63, kq = ((idx >> 6) & 7) * 4, gg = idx >> 9;
      Wg[gg][kq][ee] = pwv[p].x; Wg[gg][kq + 1][ee] = pwv[p].y; Wg[gg][kq + 2][ee] = pwv[p].z; Wg[gg][kq + 3][ee] = pwv[p].w;
    }
    __syncthreads();
    const int kn = k0 + 32;
    if (kn < E_) {
      phv = make_float4(0.f, 0.f, 0.f, 0.f);
      if (hstage && hrow >= 0 && loadH) phv = *(const float4*)&hp[(size_t)hrow * E_ + kn + hkq];
#pragma unroll
      for (int p = 0; p < 8; ++p) {
        int idx = tid + p * 256;
        int ee = idx & 63, kq = ((idx >> 6) & 7) * 4, gg = idx >> 9;
        pwv[p] = *(const float4*)&Whh[(size_t)(gg * E_ + e0 + ee) * E_ + kn + kq];
      }
    }
#pragma unroll
    for (int kk = 0; kk < 32; ++kk) {
      const float a0 = Hs[kk][cy * 2];
      const float a1 = Hs[kk][cy * 2 + 1];
#pragma unroll
      for (int gg = 0; gg < 2; ++gg) {
        const float4 w = *(const float4*)&Wg[gp * 2 + gg][kk][ex * 4];
        fma4(acc4[gg][0], a0, w);
        fma4(acc4[gg][1], a1, w);
      }
    }
    __syncthreads();
  }
#pragma unroll
  for (int gg = 0; gg < 2; ++gg) {
    *(float4*)&zb[gp * 2 + gg][cy * 2 + 0][ex * 4] = acc4[gg][0];
    *(float4*)&zb[gp * 2 + gg][cy * 2 + 1][ex * 4] = acc4[gg][1];
  }
  __syncthreads();
  const int lpos = dir ? (L_ - 1 - t) : t;
  const float* xz_dir = xz + (size_t)dir * VOC_ * E4_;
  float* c_state = c_st + (size_t)dir * C_ * E_;
  float* hn_out = h_next + (size_t)dir * C_ * E_;
  float* hall = dir ? hb_all : hf_all;
  const int oc = tid >> 4, oe = (tid & 15) * 4;
  const int lc = c0 + oc;
  int c = -1;
  if (dir == 0) { if (lc < nact) c = perm[lc]; }
  else if (lc < C_) c = lc;
  if (c >= 0) {
    const int e = e0 + oe;
    const int tok = ctx_idxs[c * L_ + lpos];
    const float* xr = xz_dir + (size_t)tok * E4_;
    float zi[4], zf[4], zg[4], zo[4], cp[4], cn[4], hn[4];
    *(float4*)zi = *(const float4*)&xr[e];
    *(float4*)zf = *(const float4*)&xr[E_ + e];
    *(float4*)zg = *(const float4*)&xr[2 * E_ + e];
    *(float4*)zo = *(const float4*)&xr[3 * E_ + e];
    if (loadH) *(float4*)cp = *(const float4*)&c_state[(size_t)c * E_ + e];
    else { cp[0] = cp[1] = cp[2] = cp[3] = 0.f; }
#pragma unroll
    for (int j = 0; j < 4; ++j) {
      float vi = zi[j] + zb[0][oc][oe + j];
      float vf = zf[j] + zb[1][oc][oe + j];
      float vg = zg[j] + zb[2][oc][oe + j];
      float vo = zo[j] + zb[3][oc][oe + j];
      cn[j] = fsig(vf) * cp[j] + fsig(vi) * ftanh(vg);
      hn[j] = fsig(vo) * ftanh(cn[j]);
    }
    *(float4*)&c_state[(size_t)c * E_ + e] = *(float4*)cn;
    *(float4*)&hn_out[(size_t)c * E_ + e] = *(float4*)hn;
    *(float4*)&hall[((size_t)c * L_ + lpos) * E_ + e] = *(float4*)hn;
  }
}

// ---------------- masked mean over L of concat(hf,hb) ----------------
__global__ __launch_bounds__(256) void k_ctx_mean(
    const float* __restrict__ hf_all, const float* __restrict__ hb_all,
    const int* __restrict__ ilens, float* __restrict__ cat_mean) {
  int idx = blockIdx.x * 256 + threadIdx.x;
  if (idx >= C_ * 2 * E_) return;
  int c = idx / (2 * E_), e = idx - c * 2 * E_;
  const float* src = (e < E_) ? hf_all : hb_all;
  int ee = e & (E_ - 1);
  int il = ilens[c];
  float s = 0.f;
#pragma unroll
  for (int l = 0; l < L_; ++l)
    if (l < il) s += src[((size_t)c * L_ + l) * E_ + ee];
  cat_mean[idx] = s / (float)il;
}

// ---------------- hist LSTM step v2: 64 blocks x 256 thr ----------------
__global__ __launch_bounds__(256) void k_hist_step2(
    const float* __restrict__ xproj, const float* __restrict__ Whh,
    const float* __restrict__ hprev, float* __restrict__ hcur,
    float* __restrict__ cstG, float* __restrict__ hall, int u) {
  __shared__ float Wl[32][516];
  __shared__ float hb[8][520];
  const int tid = threadIdx.x;
  const int e0 = blockIdx.x * 8;
  {
    int lr = tid >> 3, part = tid & 7;
    int g2 = lr >> 3, e2 = lr & 7;
    const float* src = Whh + (size_t)(g2 * D_ + e0 + e2) * D_;
#pragma unroll
    for (int i = 0; i < 16; ++i) {
      int k4 = part + i * 8;
      *(float4*)&Wl[lr][k4 * 4] = *(const float4*)&src[k4 * 4];
    }
  }
  {
    int b2 = tid >> 5, part = tid & 31;
#pragma unroll
    for (int i = 0; i < 4; ++i) {
      int k4 = part + i * 32;
      float4 v = make_float4(0.f, 0.f, 0.f, 0.f);
      if (u > 0) v = *(const float4*)&hprev[(size_t)b2 * D_ + k4 * 4];
      *(float4*)&hb[b2][k4 * 4] = v;
    }
  }
  __syncthreads();
  const int b = tid >> 5, g = (tid >> 3) & 3, e = tid & 7;
  const int lr = tid & 31;
  float dot = 0.f;
#pragma unroll 8
  for (int k4 = 0; k4 < 128; ++k4) {
    float4 w = *(const float4*)&Wl[lr][k4 * 4];
    float4 h4 = *(const float4*)&hb[b][k4 * 4];
    dot += w.x * h4.x + w.y * h4.y + w.z * h4.z + w.w * h4.w;
  }
  float z = dot + xproj[((size_t)b * U_ + u) * D4_ + g * D_ + e0 + e];
  const int l = tid & 63;
  const int base = (l & 32) | e;
  float zi = __shfl(z, base, 64);
  float zf = __shfl(z, base + 8, 64);
  float zg = __shfl(z, base + 16, 64);
  float zo = __shfl(z, base + 24, 64);
  if (g == 0) {
    float cp = (u > 0) ? cstG[(size_t)b * D_ + e0 + e] : 0.f;
    float cn = fsig(zf) * cp + fsig(zi) * ftanh(zg);
    cstG[(size_t)b * D_ + e0 + e] = cn;
    float hv = fsig(zo) * ftanh(cn);
    hcur[(size_t)b * D_ + e0 + e] = hv;
    hall[((size_t)b * U_ + u) * D_ + e0 + e] = hv;
  }
}

// ---------------- row-wise exp: Sm->EM / Sh->EH in place (+ head-sums) ----------------
__global__ __launch_bounds__(256) void k_rowexp(
    float* __restrict__ Sm, float* __restrict__ Sh,
    float* __restrict__ SmS, float* __restrict__ ShS) {
  int row = blockIdx.x;
  float* base; float* sumo;
  if (row < B_ * T_) { base = Sm + (size_t)row * HC_; sumo = SmS + (size_t)row * C_; }
  else { int r2 = row - B_ * T_; base = Sh + (size_t)r2 * HC_; sumo = ShS + (size_t)r2 * C_; }
  int tid = threadIdx.x;
  for (int c = tid; c < C_; c += 256) {
    float s = base[c] + base[C_ + c] + base[2 * C_ + c] + base[3 * C_ + c];
    sumo[c] = 0.25f * s;
  }
  __syncthreads();
  int h = tid >> 6, lane = tid & 63;
  float* p = base + (size_t)h * C_;
  float mx = -1e30f;
  for (int c = lane; c < C_; c += 64) mx = fmaxf(mx, p[c]);
#pragma unroll
  for (int o = 32; o; o >>= 1) mx = fmaxf(mx, __shfl_xor(mx, o));
  for (int c = lane; c < C_; c += 64) p[c] = __expf(p[c] - mx);
}

// ---------------- prob/logit streaming writes + den (fused) + decode bits ----------------
__global__ __launch_bounds__(256) void k_plw(
    const float* __restrict__ EM, const float* __restrict__ EH,
    const float* __restrict__ SmS, const float* __restrict__ ShS,
    const int* __restrict__ hidx,
    float* __restrict__ den, float* __restrict__ prob, float* __restrict__ logit,
    unsigned char* __restrict__ bits) {
  __shared__ float sEM[H_][1008];
  __shared__ float sSS[1000];
  __shared__ float sB[4], sT[4];
  __shared__ float sW[4][4];
  __shared__ float sInvU[4];
  const int bt = blockIdx.x >> 2;
  const int ug = blockIdx.x & 3;
  const int b = bt >> 7;
  const int tid = threadIdx.x;
  for (int i = tid; i < H_ * C_; i += 256) sEM[i / C_][i % C_] = EM[(size_t)bt * HC_ + i];
  for (int c = tid; c < C_; c += 256) sSS[c] = SmS[(size_t)bt * C_ + c];
  __syncthreads();
#pragma unroll
  for (int j = 0; j < 4; ++j) {
    const int u = ug * 4 + j;
    const int valid = (u + 1 < U_ - 1) ? (u + 1) : (U_ - 1);
    const int tok = hidx[b * U_ + valid];
    const float* eh0 = EH + ((size_t)b * U_ + u) * HC_;
    float d0 = 0.f, d1 = 0.f, d2 = 0.f, d3 = 0.f;
    for (int c = tid; c < C_; c += 256) {
      d0 += sEM[0][c] * eh0[c];
      d1 += sEM[1][c] * eh0[C_ + c];
      d2 += sEM[2][c] * eh0[2 * C_ + c];
      d3 += sEM[3][c] * eh0[3 * C_ + c];
    }
#pragma unroll
    for (int o = 32; o; o >>= 1) {
      d0 += __shfl_xor(d0, o); d1 += __shfl_xor(d1, o);
      d2 += __shfl_xor(d2, o); d3 += __shfl_xor(d3, o);
    }
    const int wv = tid >> 6;
    if ((tid & 63) == 0) { sW[wv][0] = d0; sW[wv][1] = d1; sW[wv][2] = d2; sW[wv][3] = d3; }
    __syncthreads();
    if (tid < 4) {
      float dd = sW[0][tid] + sW[1][tid] + sW[2][tid] + sW[3][tid];
      den[((size_t)bt * U_ + u) * H_ + tid] = dd;
      sInvU[tid] = 0.25f / dd;
    }
    __syncthreads();
    const float i0 = sInvU[0], i1 = sInvU[1], i2 = sInvU[2], i3 = sInvU[3];
    const float* shs = ShS + ((size_t)b * U_ + u) * C_;
    size_t obase = ((size_t)bt * U_ + u) * C_;
    for (int c = tid; c < C_; c += 256) {
      float pr = sEM[0][c] * eh0[c] * i0 + sEM[1][c] * eh0[C_ + c] * i1
               + sEM[2][c] * eh0[2 * C_ + c] * i2 + sEM[3][c] * eh0[3 * C_ + c] * i3;
      __builtin_nontemporal_store(pr, &prob[obase + c]);
      __builtin_nontemporal_store(sSS[c] + shs[c], &logit[obase + c]);
      if (c == 0) sB[j] = pr;
      if (c == tok) sT[j] = pr;
    }
    __syncthreads();
  }
  if (tid < 4) bits[bt * U_ + ug * 4 + tid] = (sT[tid] > sB[tid]) ? 1 : 0;
}

// ---------------- decode scan ----------------
__global__ __launch_bounds__(64) void k_scan(
    const unsigned char* __restrict__ bits, int* __restrict__ u_sel) {
  __shared__ unsigned char sb[B_ * T_ * U_];
  int tid = threadIdx.x;
  for (int i = tid; i < B_ * T_ * U_; i += 64) sb[i] = bits[i];
  __syncthreads();
  if (tid < B_) {
    int u = 0;
    for (int t = 0; t < T_; ++t) {
      int uc = (u < U_ - 1) ? u : (U_ - 1);
      u_sel[tid * T_ + t] = uc;
      u = uc + (int)sb[(tid * T_ + t) * U_ + uc];
    }
  }
}

// ---------------- PV on SELECTED rows, split-c partials ----------------
__global__ __launch_bounds__(256) void k_pvg2(
    const float* __restrict__ EM, const float* __restrict__ EH,
    const float* __restrict__ den, const int* __restrict__ u_sel,
    const float* __restrict__ vmat, float* __restrict__ pvp) {
  constexpr int KC = 64;
  __shared__ float wS[2][4][4][KC + 4];
  __shared__ float invS[8][4];
  __shared__ int bS[8], tS[8], uS[8];
  const int tid = threadIdx.x;
  const int cblk = blockIdx.y;
  if (tid < 32) {
    int g8 = tid >> 2, hh = tid & 3;
    int bt = blockIdx.x * 8 + g8;
    int b = bt >> 7, t = bt & 127;
    int u = u_sel[bt];
    if (hh == 0) { bS[g8] = b; tS[g8] = t; uS[g8] = u; }
    invS[g8][hh] = 1.f / den[((size_t)bt * U_ + u) * H_ + hh];
  }
  __syncthreads();
  const int sub = tid >> 7, lt = tid & 127;
  const int d = lt * 4;
  const int h = lt >> 5;
  float4 acc[4];
  acc[0] = acc[1] = acc[2] = acc[3] = make_float4(0.f, 0.f, 0.f, 0.f);
  const int cbeg = cblk * 128;
  const int cend = (cbeg + 128 < C_) ? (cbeg + 128) : C_;
  for (int c0 = cbeg; c0 < cend; c0 += KC) {
#pragma unroll
    for (int p = 0; p < 8; ++p) {
      int idx = tid + p * 256;
      int cc = idx & 63;
      int rest = idx >> 6;
      int hh = rest & 3, gg = (rest >> 2) & 3, ss = rest >> 4;
      int g8 = ss * 4 + gg;
      int c = c0 + cc;
      float w = 0.f;
      if (c < C_) {
        int b = bS[g8], t = tS[g8], u = uS[g8];
        float em = EM[(((size_t)b * T_ + t) * H_ + hh) * C_ + c];
        float eh = EH[(((size_t)b * U_ + u) * H_ + hh) * C_ + c];
        w = em * eh * invS[g8][hh];
      }
      wS[ss][gg][hh][cc] = w;
    }
    __syncthreads();
#pragma unroll 4
    for (int q = 0; q < KC / 4; ++q) {
      const float4 w0 = *(const float4*)&wS[sub][0][h][q * 4];
      const float4 w1 = *(const float4*)&wS[sub][1][h][q * 4];
      const float4 w2 = *(const float4*)&wS[sub][2][h][q * 4];
      const float4 w3 = *(const float4*)&wS[sub][3][h][q * 4];
      int c = c0 + q * 4;
      float4 v;
      if (c < C_) { v = *(const float4*)&vmat[(size_t)c * D_ + d];
        fma4(acc[0], w0.x, v); fma4(acc[1], w1.x, v); fma4(acc[2], w2.x, v); fma4(acc[3], w3.x, v); }
      if (c + 1 < C_) { v = *(const float4*)&vmat[(size_t)(c + 1) * D_ + d];
        fma4(acc[0], w0.y, v); fma4(acc[1], w1.y, v); fma4(acc[2], w2.y, v); fma4(acc[3], w3.y, v); }
      if (c + 2 < C_) { v = *(const float4*)&vmat[(size_t)(c + 2) * D_ + d];
        fma4(acc[0], w0.z, v); fma4(acc[1], w1.z, v); fma4(acc[2], w2.z, v); fma4(acc[3], w3.z, v); }
      if (c + 3 < C_) { v = *(const float4*)&vmat[(size_t)(c + 3) * D_ + d];
        fma4(acc[0], w0.w, v); fma4(acc[1], w1.w, v); fma4(acc[2], w2.w, v); fma4(acc[3], w3.w, v); }
    }
    __syncthreads();
  }
  float* pout = pvp + (size_t)cblk * PVSLAB;
#pragma unroll
  for (int g = 0; g < 4; ++g) {
    int bt = (bS[sub * 4 + g] << 7) + tS[sub * 4 + g];
    *(float4*)&pout[(size_t)bt * D_ + d] = acc[g];
  }
}

// ---------------- reduce 8 partials -> aout ----------------
__global__ __launch_bounds__(256) void k_pvred(
    const float* __restrict__ pvp, float* __restrict__ aout) {
  const size_t i = ((size_t)blockIdx.x * 256 + threadIdx.x) * 4;
  float4 s = *(const float4*)&pvp[i];
#pragma unroll
  for (int k = 1; k < 8; ++k) {
    const float4 v = *(const float4*)&pvp[(size_t)k * PVSLAB + i];
    s.x += v.x; s.y += v.y; s.z += v.z; s.w += v.w;
  }
  *(float4*)&aout[i] = s;
}

// ---------------- host launch ----------------
extern "C" void kernel_launch(void* const* d_in, const int* in_sizes, int n_in,
                              void* d_out, int out_size, void* d_ws, size_t ws_size,
                              hipStream_t stream) {
  const float* model_embed = (const float*)d_in[0];
  const float* emb_table   = (const float*)d_in[1];
  const float* Wih_f = (const float*)d_in[2];
  const float* Whh_f = (const float*)d_in[3];
  const float* b_f   = (const float*)d_in[4];
  const float* Wih_b = (const float*)d_in[5];
  const float* Whh_b = (const float*)d_in[6];
  const float* b_b   = (const float*)d_in[7];
  const float* ctx_out_W  = (const float*)d_in[8];
  const float* hist_Wih   = (const float*)d_in[9];
  const float* hist_Whh   = (const float*)d_in[10];
  const float* hist_b     = (const float*)d_in[11];
  const float* hist_out_W = (const float*)d_in[12];
  const float* Wq = (const float*)d_in[13];
  const float* Wk = (const float*)d_in[14];
  const float* Wv = (const float*)d_in[15];
  const float* Wo = (const float*)d_in[16];
  const float* acoustic_W = (const float*)d_in[17];
  const int* ctx_idxs = (const int*)d_in[18];
  const int* hidx     = (const int*)d_in[19];
  const int* ilens    = (const int*)d_in[20];

  if (ws_size < WS_NEED * sizeof(float)) return;

  float* ws = (float*)d_ws;
  float* o_out     = (float*)d_out;
  float* logit_out = o_out + (size_t)B_ * T_ * D_;
  float* prob_out  = logit_out + (size_t)B_ * T_ * U_ * C_;

  // ---- perm for fwd dead-row elimination ----
  k_perm<<<dim3(1), 256, 0, stream>>>(ilens, (int*)(ws + PERM_), (int*)(ws + NACT_));

  // ---- weight folding ----
  k_gemm_nn<<<dim3(8, 8, 2), 256, 0, stream>>>(
      Wq, acoustic_W, ws + WQA, Wq, hist_out_W, ws + WQH);

  // ---- ctx LSTM input projections, whole vocab, both dirs ----
  {
    GemmP pf{};
    pf.A1 = emb_table; pf.lda1 = E_;
    pf.W1 = Wih_f; pf.ldw1 = E_;
    pf.bias = b_f;
    pf.out = ws + XZ_; pf.ldc = E4_;
    pf.M = VOC_; pf.N = E4_; pf.K = E_; pf.scale = 1.f;
    GemmP pb = pf;
    pb.W1 = Wih_b; pb.bias = b_b; pb.out = ws + XZ_ + (size_t)VOC_ * E4_;
    k_gemm64xcd<<<dim3(XZ_NWG, 1, 2), 256, 0, stream>>>(pf, pb);
  }

  // ---- ctx LSTM recurrence: 8 per-step launches (fwd compacted, t0 zero-state) ----
  for (int t = 0; t < L_; ++t) {
    float* hp = ws + ((t & 1) ? HPONG : HPING);
    float* hn = ws + ((t & 1) ? HPING : HPONG);
    k_ctx_step<<<dim3(4, (C_ + 15) / 16, 2), 256, 0, stream>>>(
        ws + XZ_, ctx_idxs, Whh_f, Whh_b, hp, hn, ws + CST,
        ws + HFALL, ws + HBALL,
        (const int*)(ws + PERM_), (const int*)(ws + NACT_), t);
  }

  // ---- masked mean + ctx_out projection ----
  k_ctx_mean<<<dim3((C_ * 2 * E_ + 255) / 256), 256, 0, stream>>>(
      ws + HFALL, ws + HBALL, ilens, ws + CATM);
  {
    GemmP p{};
    p.A1 = ws + CATM; p.lda1 = 2 * E_;
    p.W1 = ctx_out_W; p.ldw1 = 2 * E_;
    p.out = ws + CTXM; p.ldc = D_; p.M = C_; p.N = D_; p.K = 2 * E_; p.scale = 1.f;
    k_gemm64<<<dim3(8, 16, 1), 256, 0, stream>>>(p);
  }

  // ---- k (scaled), v, hist input projection ----
  {
    GemmP pk{};
    pk.A1 = ws + CTXM; pk.lda1 = D_;
    pk.W1 = Wk; pk.ldw1 = D_;
    pk.out = ws + KWS; pk.ldc = D_; pk.M = C_; pk.N = D_; pk.K = D_; pk.scale = SCALE_;
    GemmP pv = pk;
    pv.W1 = Wv; pv.out = ws + VWS; pv.scale = 1.f;
    GemmP ph{};
    ph.A1 = ws + CTXM; ph.lda1 = D_;
    ph.ridx = hidx; ph.ridx_stride = 1; ph.ridx_off = 0;
    ph.W1 = hist_Wih; ph.ldw1 = D_;
    ph.bias = hist_b;
    ph.out = ws + HXP; ph.ldc = D4_; ph.M = B_ * U_; ph.N = D4_; ph.K = D_; ph.scale = 1.f;
    k_gemm64x3<<<dim3(32, 16, 3), 256, 0, stream>>>(pk, pv, ph);
  }

  // ---- hist LSTM recurrence: 16 per-step launches ----
  for (int u = 0; u < U_; ++u) {
    const float* hp = ws + ((u & 1) ? HG2 : HGLOB);
    float* hc = ws + ((u & 1) ? HGLOB : HG2);
    k_hist_step2<<<dim3(64), 256, 0, stream>>>(
        ws + HXP, hist_Whh, hp, hc, ws + HISTC, ws + HALL, u);
  }

  // ---- qm, qh ----
  {
    GemmP pm{};
    pm.A1 = model_embed; pm.lda1 = D_;
    pm.W1 = ws + WQA; pm.ldw1 = D_;
    pm.out = ws + QM_; pm.ldc = D_; pm.M = B_ * T_; pm.N = D_; pm.K = D_; pm.scale = 1.f;
    GemmP ph = pm;
    ph.A1 = ws + HALL; ph.W1 = ws + WQH; ph.out = ws + QH_; ph.M = B_ * U_;
    k_gemm64x2<<<dim3(8, 16, 2), 256, 0, stream>>>(pm, ph, 1);
  }

  // ---- Sm, Sh (per-head via z, pipelined 128-core) ----
  {
    GemmP pm{};
    pm.A1 = ws + QM_; pm.lda1 = D_;
    pm.W1 = ws + KWS; pm.ldw1 = D_;
    pm.out = ws + SM_; pm.ldc = HC_; pm.M = B_ * T_; pm.N = C_; pm.K = DH_; pm.scale = 1.f;
    pm.a_zoff = DH_; pm.w_zoff = DH_; pm.c_zoff = C_;
    GemmP ph = pm;
    ph.A1 = ws + QH_; ph.out = ws + SH_; ph.M = B_ * U_;
    k_gemm128x2<<<dim3(8, 16, 8), 256, 0, stream>>>(pm, ph, 4);
  }

  // ---- exp factorization ----
  k_rowexp<<<dim3(B_ * T_ + B_ * U_), 256, 0, stream>>>(
      ws + SM_, ws + SH_, ws + SMSUM, ws + SHSUM);

  // ---- prob/logit streaming writes + fused den + bits ----
  k_plw<<<dim3(B_ * T_ * 4), 256, 0, stream>>>(
      ws + SM_, ws + SH_, ws + SMSUM, ws + SHSUM, hidx,
      ws + DEN_, prob_out, logit_out, (unsigned char*)(ws + BITS_));

  // ---- decode scan ----
  k_scan<<<dim3(1), 64, 0, stream>>>((const unsigned char*)(ws + BITS_), (int*)(ws + USEL_));

  // ---- PV on selected rows (split-c) + reduce ----
  k_pvg2<<<dim3(128, 8), 256, 0, stream>>>(
      ws + SM_, ws + SH_, ws + DEN_, (const int*)(ws + USEL_), ws + VWS, ws + PVP_);
  k_pvred<<<dim3((B_ * T_ * D_) / (256 * 4)), 256, 0, stream>>>(ws + PVP_, ws + AOUT_);

  // ---- Wo projection -> o ----
  {
    GemmP p{};
    p.A1 = ws + AOUT_; p.lda1 = D_;
    p.W1 = Wo; p.ldw1 = D_;
    p.out = o_out; p.ldc = D_; p.M = B_ * T_; p.N = D_; p.K = D_; p.scale = 1.f;
    k_gemm64<<<dim3(8, 16, 1), 256, 0, stream>>>(p);
  }
}